// Round 6
// baseline (372.011 us; speedup 1.0000x reference)
//
#include <hip/hip_runtime.h>

typedef unsigned short u16;
typedef __attribute__((ext_vector_type(8))) short bf16x8;
typedef __attribute__((ext_vector_type(4))) float f32x4;
typedef __attribute__((ext_vector_type(16))) float f32x16;
typedef int i32x2 __attribute__((ext_vector_type(2)));

__device__ __forceinline__ float bf2f(u16 u) {
  union { unsigned int i; float f; } x; x.i = ((unsigned int)u) << 16; return x.f;
}
__device__ __forceinline__ u16 f2bf(float f) {
  union { float f; unsigned int i; } x; x.f = f;
  unsigned int r = x.i + 0x7fffu + ((x.i >> 16) & 1u);
  return (u16)(r >> 16);
}

#define CFENCE() asm volatile("" ::: "memory")

__device__ __forceinline__ unsigned cvtpk_bf16(float lo, float hi) {
  unsigned r;
  asm("v_cvt_pk_bf16_f32 %0, %1, %2" : "=v"(r) : "v"(lo), "v"(hi));
  return r;
}

// ---------------------------------------------------------------------------
// Merged pooling + m f32->bf16 convert. Blocks [0,9944): pool; rest: convert.
// ---------------------------------------------------------------------------
__global__ __launch_bounds__(256) void k_pool(
    const float* __restrict__ x, u16* __restrict__ pool,
    const float* __restrict__ m, u16* __restrict__ mb)
{
  int blk = blockIdx.x;
  if (blk >= 9944) {                      // f2b segment (m -> mb)
    size_t i = ((size_t)(blk - 9944) * 256 + threadIdx.x) * 8;
    float4 a = *(const float4*)(m + i);
    float4 b = *(const float4*)(m + i + 4);
    ushort4 u0, u1;
    u0.x = f2bf(a.x); u0.y = f2bf(a.y); u0.z = f2bf(a.z); u0.w = f2bf(a.w);
    u1.x = f2bf(b.x); u1.y = f2bf(b.y); u1.z = f2bf(b.z); u1.w = f2bf(b.w);
    *(ushort4*)(mb + i) = u0;
    *(ushort4*)(mb + i + 4) = u1;
    return;
  }
  int b = blk / 1243;
  int tok = blk - b * 1243;
  int c = threadIdx.x;
  const float* xb = x + (size_t)b * 4096 * 512;
  float r0, r1;
  if (tok >= 987) {                       // maxpool 16x16, 4x4 windows
    int t = tok - 987;
    int oh = t >> 4, ow = t & 15;
    float m0 = -1e38f, m1 = -1e38f;
    for (int hh = 0; hh < 4; hh++)
      for (int ww = 0; ww < 4; ww++) {
        const float* px = xb + (size_t)((oh * 4 + hh) * 64 + ow * 4 + ww) * 512 + c;
        m0 = fmaxf(m0, px[0]);
        m1 = fmaxf(m1, px[256]);
      }
    r0 = m0; r1 = m1;
  } else {                                // adaptive avg, 4 scales
    int n, t;
    if (tok < 441)      { n = 21; t = tok; }
    else if (tok < 697) { n = 16; t = tok - 441; }
    else if (tok < 866) { n = 13; t = tok - 697; }
    else                { n = 11; t = tok - 866; }
    int oh = t / n, ow = t - oh * n;
    int h0 = (oh * 64) / n, h1 = ((oh + 1) * 64 + n - 1) / n;
    int w0 = (ow * 64) / n, w1 = ((ow + 1) * 64 + n - 1) / n;
    float inv = 1.0f / (float)((h1 - h0) * (w1 - w0));
    float s0 = 0.f, s1 = 0.f;
    for (int hh = h0; hh < h1; hh++)
      for (int ww = w0; ww < w1; ww++) {
        const float* px = xb + (size_t)(hh * 64 + ww) * 512 + c;
        s0 += px[0];
        s1 += px[256];
      }
    r0 = s0 * inv; r1 = s1 * inv;
  }
  u16* dst = pool + (size_t)(b * 1243 + tok) * 512 + c;
  dst[0]   = f2bf(r0);
  dst[256] = f2bf(r1);
}

// ---------------------------------------------------------------------------
// Merged weight transpose+convert: all 8 weight matrices in one launch.
// ---------------------------------------------------------------------------
__global__ __launch_bounds__(256) void k_wt8(
    const float* w0, const float* w1, const float* w2, const float* w3,
    const float* w4, const float* w5, const float* w6, const float* w7,
    u16* __restrict__ wt_base)
{
  int z = blockIdx.z;
  int N = (z == 6) ? 1024 : 512;
  if (N == 512 && blockIdx.x >= 16) return;
  const float* W =
      z == 0 ? w0 : z == 1 ? w1 : z == 2 ? w2 : z == 3 ? w3 :
      z == 4 ? w4 : z == 5 ? w5 : z == 6 ? w6 : w7;
  size_t doff = (z <= 5) ? (size_t)z * 262144
                         : (z == 6 ? (size_t)6 * 262144 : (size_t)6 * 262144 + 524288);
  u16* Wt = wt_base + doff;

  __shared__ float tile[32][33];
  int n0 = blockIdx.x * 32, k0 = blockIdx.y * 32;
  int t = threadIdx.x;
  int rr = t >> 5, cc = t & 31;
#pragma unroll
  for (int ps = 0; ps < 4; ps++)
    tile[ps * 8 + rr][cc] = W[(size_t)(k0 + ps * 8 + rr) * N + n0 + cc];
  __syncthreads();
#pragma unroll
  for (int ps = 0; ps < 4; ps++)
    Wt[(size_t)(n0 + ps * 8 + rr) * 512 + k0 + cc] = f2bf(tile[cc][ps * 8 + rr]);
}

// ---------------------------------------------------------------------------
// Pipelined MFMA GEMM core (128x128, BK=32, 4 waves, 2-phase, raw barriers)
// ---------------------------------------------------------------------------
template <class EPI>
__device__ __forceinline__ void gemm_core(
    const u16* __restrict__ Az, const u16* __restrict__ Bt,
    int M, int K, int m0, int n0, EPI&& epi)
{
  __shared__ __align__(16) u16 As[128][40];
  __shared__ __align__(16) u16 Bs[128][40];

  const int tid = threadIdx.x;
  const int lane = tid & 63, wv = tid >> 6;
  const int quad = lane >> 4, l15 = lane & 15;
  const int wm = (wv >> 1) * 64, wn = (wv & 1) * 64;

  f32x4 acc[4][4];
#pragma unroll
  for (int i = 0; i < 4; i++)
#pragma unroll
    for (int j = 0; j < 4; j++) acc[i][j] = (f32x4){0.f, 0.f, 0.f, 0.f};

  const int srow = tid >> 1;
  const int scol = (tid & 1) * 16;
  const bool aok = (m0 + srow) < M;
  const u16* ag = Az + (size_t)(m0 + srow) * K + scol;
  const u16* bg = Bt + (size_t)(n0 + srow) * K + scol;

  uint4 a0 = {0, 0, 0, 0}, a1 = {0, 0, 0, 0}, b0, b1;
  if (aok) { a0 = *(const uint4*)ag; a1 = *(const uint4*)(ag + 8); }
  b0 = *(const uint4*)bg;
  b1 = *(const uint4*)(bg + 8);

  for (int k0 = 0; k0 < K; k0 += 32) {
    CFENCE();
    __builtin_amdgcn_s_barrier();
    asm volatile("s_waitcnt vmcnt(0)" ::: "memory");
    *(uint4*)&As[srow][scol]     = a0;
    *(uint4*)&As[srow][scol + 8] = a1;
    *(uint4*)&Bs[srow][scol]     = b0;
    *(uint4*)&Bs[srow][scol + 8] = b1;
    if (k0 + 32 < K) {
      if (aok) { a0 = *(const uint4*)(ag + k0 + 32); a1 = *(const uint4*)(ag + k0 + 40); }
      b0 = *(const uint4*)(bg + k0 + 32);
      b1 = *(const uint4*)(bg + k0 + 40);
    }
    asm volatile("s_waitcnt lgkmcnt(0)" ::: "memory");
    __builtin_amdgcn_s_barrier();
    CFENCE();

    bf16x8 af[4];
#pragma unroll
    for (int i = 0; i < 4; i++)
      af[i] = *(const bf16x8*)&As[wm + i * 16 + l15][quad * 8];
#pragma unroll
    for (int j = 0; j < 4; j++) {
      bf16x8 bfj = *(const bf16x8*)&Bs[wn + j * 16 + l15][quad * 8];
#pragma unroll
      for (int i = 0; i < 4; i++)
        acc[i][j] = __builtin_amdgcn_mfma_f32_16x16x32_bf16(af[i], bfj, acc[i][j], 0, 0, 0);
    }
  }

#pragma unroll
  for (int i = 0; i < 4; i++) {
    int rb = m0 + wm + i * 16 + quad * 4;
#pragma unroll
    for (int j = 0; j < 4; j++) {
      int col = n0 + wn + j * 16 + l15;
#pragma unroll
      for (int r = 0; r < 4; r++) {
        int row = rb + r;
        if (row >= M) continue;
        epi(row, col, acc[i][j][r]);
      }
    }
  }
}

// f32 output + bias (final projection)
__global__ __launch_bounds__(256) void k_gemm_f32(
    const u16* __restrict__ A, long long a_bs, const u16* __restrict__ Bt,
    const float* __restrict__ bias, float* __restrict__ C, long long c_bs,
    int M, int N, int K)
{
  const u16* Az = A + (size_t)blockIdx.z * a_bs;
  float* Cz = C + (size_t)blockIdx.z * c_bs;
  gemm_core(Az, Bt, M, K, blockIdx.y * 128, blockIdx.x * 128,
            [&](int row, int col, float v) {
              Cz[(size_t)row * N + col] = v + bias[col];
            });
}

// merged q|KV-from-m (y<8) and KV-from-LN(p) (y>=8) GEMMs, one launch
__global__ __launch_bounds__(256) void k_gemm_big(
    const u16* __restrict__ mb, const u16* __restrict__ p,
    const u16* __restrict__ wqkv, const u16* __restrict__ wkv,
    u16* __restrict__ q, u16* __restrict__ KV)
{
  int y = blockIdx.y, z = blockIdx.z;
  if (y < 8) {
    const u16* Az = mb + (size_t)z * (1024 * 512);
    u16* qz  = q  + (size_t)z * (1024 * 512);
    u16* kvz = KV + (size_t)(z * 2267 + 1243) * 1024;
    gemm_core(Az, wqkv, 1024, 512, y * 128, blockIdx.x * 128,
              [&](int row, int col, float v) {
                u16 bv = f2bf(v);
                if (col < 512) qz[(size_t)row * 512 + col] = bv;
                else           kvz[(size_t)row * 1024 + (col - 512)] = bv;
              });
  } else {
    if (blockIdx.x >= 8) return;
    const u16* Az = p + (size_t)z * (1243 * 512);
    u16* kvz = KV + (size_t)z * 2267 * 1024;
    gemm_core(Az, wkv, 1243, 512, (y - 8) * 128, blockIdx.x * 128,
              [&](int row, int col, float v) {
                kvz[(size_t)row * 1024 + col] = f2bf(v);
              });
  }
}

// Segmented conv GEMM (5 residual 1x1 convs) + fused mx transpose-out (s==4)
__global__ __launch_bounds__(256) void k_conv_seg(
    const u16* __restrict__ pool, const u16* __restrict__ wts,
    const float* b0, const float* b1, const float* b2, const float* b3,
    const float* b4, u16* __restrict__ p, float* __restrict__ out2)
{
  int y = blockIdx.y, bz = blockIdx.z;
  int s, m0;
  if (y < 4)      { s = 0; m0 = y * 128; }
  else if (y < 6) { s = 1; m0 = (y - 4) * 128; }
  else if (y < 8) { s = 2; m0 = (y - 6) * 128; }
  else if (y < 9) { s = 3; m0 = 0; }
  else            { s = 4; m0 = (y - 9) * 128; }
  int t0  = s == 0 ? 0 : s == 1 ? 441 : s == 2 ? 697 : s == 3 ? 866 : 987;
  int cnt = s == 0 ? 441 : s == 1 ? 256 : s == 2 ? 169 : s == 3 ? 121 : 256;
  const float* bias = s == 0 ? b0 : s == 1 ? b1 : s == 2 ? b2 : s == 3 ? b3 : b4;
  size_t base = (size_t)bz * (1243 * 512) + (size_t)t0 * 512;
  const u16* Az = pool + base;
  u16* Cz = p + base;
  gemm_core(Az, wts + (size_t)s * 262144, cnt, 512, m0, blockIdx.x * 128,
            [&](int row, int col, float v) {
              v += bias[col] + bf2f(Az[(size_t)row * 512 + col]);
              Cz[(size_t)row * 512 + col] = f2bf(v);
              if (s == 4)                           // mx output [B][C][256] f32
                out2[((size_t)(bz * 512 + col)) * 256 + row] = v;
            });
}

// ---------------------------------------------------------------------------
// LayerNorm in place over C=512
// ---------------------------------------------------------------------------
__global__ __launch_bounds__(256) void k_ln(
    u16* __restrict__ p, const float* __restrict__ g, const float* __restrict__ bb)
{
  __shared__ float red[8];
  size_t row = blockIdx.x;
  u16* pr = p + row * 512;
  int t = threadIdx.x;
  float v0 = bf2f(pr[t]), v1 = bf2f(pr[t + 256]);
  float s = v0 + v1;
#pragma unroll
  for (int off = 1; off < 64; off <<= 1) s += __shfl_xor(s, off);
  int wave = t >> 6;
  if ((t & 63) == 0) red[wave] = s;
  __syncthreads();
  float mean = (red[0] + red[1] + red[2] + red[3]) * (1.f / 512.f);
  float d0 = v0 - mean, d1 = v1 - mean;
  float s2 = d0 * d0 + d1 * d1;
#pragma unroll
  for (int off = 1; off < 64; off <<= 1) s2 += __shfl_xor(s2, off);
  if ((t & 63) == 0) red[4 + wave] = s2;
  __syncthreads();
  float var = (red[4] + red[5] + red[6] + red[7]) * (1.f / 512.f);
  float rstd = rsqrtf(var + 1e-5f);
  pr[t]       = f2bf(d0 * rstd * g[t]       + bb[t]);
  pr[t + 256] = f2bf(d1 * rstd * g[t + 256] + bb[t + 256]);
}

// ---------------------------------------------------------------------------
// MFMA flash attention v8: 32x32x16 MFMA, 32 queries/wave (2x arithmetic
// intensity per LDS byte vs 16x16 -> halves the LDS-read bottleneck).
// 4 waves x 32 q = 128 q/block, grid 512 (XCD-local (h,b) decode).
// Swapped QK^T: mfma(K,Q) -> S^T with q = lane&31; lane holds 16 key-scores
// (rows via reg&3 + 8*(reg>>2) + 4*hl). exp2 -> cvt_pk x8 -> permlane32_swap
// x4 yields PV A-frags in NATURAL key order (no V swizzle). Max-free softmax,
// zero-pad tail => subtract 37 from l. 2-phase pipelined staging.
// LDS = Ks[64][68] + Vt[64][68] = 17408 B (34-word stride -> 2-way banks).
// ---------------------------------------------------------------------------
__global__ __launch_bounds__(256) void k_attn_mfma(
    const u16* __restrict__ qb, const u16* __restrict__ KV,
    u16* __restrict__ outb)
{
  __shared__ __align__(16) u16 Ks_[64][68];   // [key][dim]
  __shared__ __align__(16) u16 Vt_[64][68];   // [dim][key]

  const int bid = blockIdx.x;
  const int qt = bid >> 6;                  // 0..7, 128 queries each
  const int hb = bid & 63;
  const int h = hb & 7, b = hb >> 3;        // XCD-local KV decode
  const int tid = threadIdx.x;
  const int lane = tid & 63, wv = tid >> 6; // wave owns queries wv*32..+32
  const int l31 = lane & 31, hl = lane >> 5;

  const u16* kvb = KV + (size_t)b * 2267 * 1024;
  const int kr = tid >> 2, kc = (tid & 3) * 16;  // K staging: key, 16-dim chunk
  const int vp = tid & 31, vo = tid >> 5;        // V staging: key pair, dim octet

  uint4 k0r = {0,0,0,0}, k1r = {0,0,0,0}, vra = {0,0,0,0}, vrb = {0,0,0,0};
  auto load_tile = [&](int n0) {
    k0r = (uint4){0,0,0,0}; k1r = (uint4){0,0,0,0};
    vra = (uint4){0,0,0,0}; vrb = (uint4){0,0,0,0};
    if (n0 + kr < 2267) {
      const u16* s = kvb + (size_t)(n0 + kr) * 1024 + h * 64 + kc;
      k0r = *(const uint4*)s;
      k1r = *(const uint4*)(s + 8);
    }
    int na = n0 + 2 * vp;
    const u16* s = kvb + (size_t)na * 1024 + 512 + h * 64 + vo * 8;
    if (na < 2267)     vra = *(const uint4*)s;
    if (na + 1 < 2267) vrb = *(const uint4*)(s + 1024);
  };

  load_tile(0);
  // Q fragments from global: Q[q = qt*128 + wv*32 + l31][dims c*16 + hl*8 ..+8]
  bf16x8 qf[4];
  {
    const u16* qrow = qb + (size_t)(b * 1024 + qt * 128 + wv * 32 + l31) * 512
                    + h * 64 + hl * 8;
    qf[0] = *(const bf16x8*)(qrow);
    qf[1] = *(const bf16x8*)(qrow + 16);
    qf[2] = *(const bf16x8*)(qrow + 32);
    qf[3] = *(const bf16x8*)(qrow + 48);
  }

  float l_acc = 0.f;
  f32x16 o0, o1;
#pragma unroll
  for (int i = 0; i < 16; i++) { o0[i] = 0.f; o1[i] = 0.f; }

  __syncthreads();

  for (int n0 = 0; n0 < 2267; n0 += 64) {
    CFENCE();
    __builtin_amdgcn_s_barrier();                       // prev tile's readers done
    asm volatile("s_waitcnt vmcnt(0)" ::: "memory");    // this tile's regs ready
    *(uint4*)&Ks_[kr][kc]     = k0r;
    *(uint4*)&Ks_[kr][kc + 8] = k1r;
    {
      const unsigned* pa = (const unsigned*)&vra;
      const unsigned* pb = (const unsigned*)&vrb;
#pragma unroll
      for (int i = 0; i < 4; i++) {
        unsigned lo = __builtin_amdgcn_perm(pb[i], pa[i], 0x05040100u);
        unsigned hi = __builtin_amdgcn_perm(pb[i], pa[i], 0x07060302u);
        *(unsigned*)&Vt_[vo * 8 + 2 * i][2 * vp]     = lo;
        *(unsigned*)&Vt_[vo * 8 + 2 * i + 1][2 * vp] = hi;
      }
    }
    if (n0 + 64 < 2267) load_tile(n0 + 64);             // prefetch next tile
    asm volatile("s_waitcnt lgkmcnt(0)" ::: "memory");  // ds_writes done; vmem in flight
    __builtin_amdgcn_s_barrier();
    CFENCE();

    // ---- two 32-key slabs ----
#pragma unroll
    for (int s = 0; s < 2; s++) {
      f32x16 sacc;
#pragma unroll
      for (int i = 0; i < 16; i++) sacc[i] = 0.f;
      __builtin_amdgcn_s_setprio(1);
#pragma unroll
      for (int c = 0; c < 4; c++) {                      // chain over D=64
        bf16x8 kf = *(const bf16x8*)&Ks_[s * 32 + l31][c * 16 + hl * 8];
        sacc = __builtin_amdgcn_mfma_f32_32x32x16_bf16(kf, qf[c], sacc, 0, 0, 0);
      }
      __builtin_amdgcn_s_setprio(0);

      // P = exp2(S*scale*log2e); pack; permlane32_swap -> A-frags (natural order)
      unsigned w[8];
#pragma unroll
      for (int j = 0; j < 8; j++) {
        float e0 = __builtin_amdgcn_exp2f(fminf(sacc[2 * j]     * 0.18033688f, 43.28f));
        float e1 = __builtin_amdgcn_exp2f(fminf(sacc[2 * j + 1] * 0.18033688f, 43.28f));
        l_acc += e0 + e1;
        w[j] = cvtpk_bf16(e0, e1);
      }
      i32x2 s02 = __builtin_amdgcn_permlane32_swap((int)w[0], (int)w[2], false, false);
      i32x2 s13 = __builtin_amdgcn_permlane32_swap((int)w[1], (int)w[3], false, false);
      i32x2 s46 = __builtin_amdgcn_permlane32_swap((int)w[4], (int)w[6], false, false);
      i32x2 s57 = __builtin_amdgcn_permlane32_swap((int)w[5], (int)w[7], false, false);
      uint4 f0, f1;
      f0.x = (unsigned)s02[0]; f0.y = (unsigned)s13[0];
      f0.z = (unsigned)s02[1]; f0.w = (unsigned)s13[1];   // slab keys 0..15
      f1.x = (unsigned)s46[0]; f1.y = (unsigned)s57[0];
      f1.z = (unsigned)s46[1]; f1.w = (unsigned)s57[1];   // slab keys 16..31
      bf16x8 ap0 = __builtin_bit_cast(bf16x8, f0);
      bf16x8 ap1 = __builtin_bit_cast(bf16x8, f1);

      // O += P V  (B-frag: V[k = chunk + hl*8 ..+8][d = dh*32 + l31])
      __builtin_amdgcn_s_setprio(1);
      {
        bf16x8 v00 = *(const bf16x8*)&Vt_[l31][s * 32 + hl * 8];
        bf16x8 v01 = *(const bf16x8*)&Vt_[l31][s * 32 + 16 + hl * 8];
        bf16x8 v10 = *(const bf16x8*)&Vt_[32 + l31][s * 32 + hl * 8];
        bf16x8 v11 = *(const bf16x8*)&Vt_[32 + l31][s * 32 + 16 + hl * 8];
        o0 = __builtin_amdgcn_mfma_f32_32x32x16_bf16(ap0, v00, o0, 0, 0, 0);
        o0 = __builtin_amdgcn_mfma_f32_32x32x16_bf16(ap1, v01, o0, 0, 0, 0);
        o1 = __builtin_amdgcn_mfma_f32_32x32x16_bf16(ap0, v10, o1, 0, 0, 0);
        o1 = __builtin_amdgcn_mfma_f32_32x32x16_bf16(ap1, v11, o1, 0, 0, 0);
      }
      __builtin_amdgcn_s_setprio(0);
    }
  }

  // l: lane covers q=l31 over half the keys; partner lane (^32) has the rest
  l_acc += __shfl_xor(l_acc, 32);

  // epilogue: wave-local. O rows: q = (r&3) + 8*(r>>2) + 4*hl; cols: d = dh*32+l31
#pragma unroll
  for (int r = 0; r < 16; r++) {
    int qr = (r & 3) + 8 * (r >> 2) + 4 * hl;
    float lq = __shfl(l_acc, qr);              // lane qr (hl=0) holds l for q=qr
    float inv = 1.f / fmaxf(lq - 37.f, 1e-20f);
    size_t row = (size_t)(b * 1024 + qt * 128 + wv * 32 + qr);
    outb[row * 512 + h * 64 + l31]      = f2bf(o0[r] * inv);
    outb[row * 512 + h * 64 + 32 + l31] = f2bf(o1[r] * inv);
  }
}

// ---------------------------------------------------------------------------
extern "C" void kernel_launch(void* const* d_in, const int* in_sizes, int n_in,
                              void* d_out, int out_size, void* d_ws, size_t ws_size,
                              hipStream_t stream)
{
  const float* x = (const float*)d_in[0];
  const float* m = (const float*)d_in[1];
  const float* ln_g = (const float*)d_in[12];
  const float* ln_b = (const float*)d_in[13];
  const float* Wq   = (const float*)d_in[14];
  const float* Wkv  = (const float*)d_in[15];
  const float* Wp   = (const float*)d_in[16];
  const float* bp   = (const float*)d_in[17];
  float* out = (float*)d_out;  // out f32 [8,1024,512] | mx f32 [8,512,256]

  // ws (u16 units): pool | p | q | KV | mb | weight-transposes   (~79 MB)
  u16* pool = (u16*)d_ws;
  u16* p    = pool + 5091328;
  u16* q    = p + 5091328;
  u16* KV   = q + 4194304;                 // 8*2267*1024
  u16* mb   = KV + 18571264;               // 8*1024*512
  u16* wt_s = mb + 4194304;                // 5 x 512x512 | wq | wkv | wp
  u16* attn_out = pool;                    // pool dead after conv GEMMs

  // weight prep (one launch)
  k_wt8<<<dim3(32, 16, 8), 256, 0, stream>>>(
      (const float*)d_in[2], (const float*)d_in[4], (const float*)d_in[6],
      (const float*)d_in[8], (const float*)d_in[10], Wq, Wkv, Wp, wt_s);

  // pooling + m conversion, one launch
  k_pool<<<11992, 256, 0, stream>>>(x, pool, m, mb);

  // residual 1x1 convs (MFMA) + fused mx transpose-out, one launch
  k_conv_seg<<<dim3(4, 11, 8), 256, 0, stream>>>(
      pool, wt_s, (const float*)d_in[3], (const float*)d_in[5],
      (const float*)d_in[7], (const float*)d_in[9], (const float*)d_in[11],
      p, out + 4194304);

  k_ln<<<9944, 256, 0, stream>>>(p, ln_g, ln_b);

  // q | KV (both halves), one merged launch
  k_gemm_big<<<dim3(12, 18, 8), 256, 0, stream>>>(
      mb, p, wt_s + 5 * 262144, wt_s + 6 * 262144, q, KV);

  // attention: 512 blocks x 256 threads (4 waves, 32 q/wave), XCD-local decode
  k_attn_mfma<<<512, 256, 0, stream>>>(q, KV, attn_out);

  // out = attn_out @ Wp + bp -> f32 d_out
  k_gemm_f32<<<dim3(4, 8, 8), 256, 0, stream>>>(attn_out, (long long)1024 * 512,
                                                wt_s + 6 * 262144 + 524288, bp,
                                                out, (long long)1024 * 512,
                                                1024, 512, 512);
  (void)in_sizes; (void)n_in; (void)out_size; (void)ws_size;
}